// Round 5
// baseline (93.878 us; speedup 1.0000x reference)
//
#include <hip/hip_runtime.h>

// Chamfer reconstruction loss, B=16, P=Q=4096, 3-D points, via bf16 MFMA.
// d(i,j) = |q_i|^2 + |t_j|^2 - 2 q_i.t_j; cross term + |t|^2 via one
// v_mfma_f32_32x32x16_bf16 per 32x32 tile (A: a=bf16(-2q) twice + 1.0;
// B: t_hi, t_lo, |t|^2 hi/lo; fp32 accum). Query rounding error is
// per-row-constant -> cancels in argmin, averages out in the mean.
//
// R14: target-split ("split-K for min"). R9/R13 counters show the MFMA
// pipe already runs at the full algorithmic demand of 2 waves/SIMD
// (MfmaUtil 15.3% == 16.4K/99K cycles) -> latency-bound, and occupancy
// is capped by LDS (68.6KB -> 2 blocks/CU), not regs or code. Fix: each
// block stages only 2048 targets (34.6KB LDS), grid 1024 via a thalf
// bit -> 3 blocks/CU (reg-capped: ~88 VGPR + 64 AGPR), 12 waves/CU.
// Wave machinery is verbatim R13 (256 thr, 4 waves, sub-loop, 4-deep
// stream, fold). Since min(m0,m1)+q2 == min(m0+q2,m1+q2), blocks write
// per-row (mn+q2) to ws (1MB, fully overwritten -> poison-safe); a new
// minsum_kernel does pairwise min + block sums; reduce_kernel reused.

#define NB 16
#define NP 4096
#define NT 2048          // targets per block after split
#define THREADS 256
#define NROWS 131072     // 2 dirs * 16 b * 4096 rows
#define INV128 0.0078125f   // gt normalize: c/128 - 1
#define FINF __int_as_float(0x7F800000)

typedef __attribute__((ext_vector_type(8)))  short bf16x8;
typedef __attribute__((ext_vector_type(16))) float f32x16;

__device__ __forceinline__ short bf16rne(float f) {
    unsigned u = __float_as_uint(f);
    return (short)((u + 0x7FFFu + ((u >> 16) & 1u)) >> 16);
}
__device__ __forceinline__ float bf2f(short s) {
    return __uint_as_float(((unsigned)(unsigned short)s) << 16);
}

// grid = 1024: dir = bid>>9, b = (bid>>5)&15, qpair = (bid>>1)&15, thalf = bid&1.
// Block: queries [qpair*256, qpair*256+256) x targets [thalf*2048, +2048).
__global__ __launch_bounds__(THREADS) void chamfer_kernel(const float* __restrict__ gen,
                                                          const float* __restrict__ label,
                                                          float* __restrict__ rowmins) {
    // 32KB pack + zero line + prefetch-overrun pad (same layout, half targets)
    __shared__ short spack[NT * 8 + 1280];

    const int bid   = blockIdx.x;
    const int dir   = bid >> 9;
    const int b     = (bid >> 5) & 15;
    const int qpair = (bid >> 1) & 15;
    const int thalf = bid & 1;
    const int tid   = threadIdx.x;
    const int lane  = tid & 63;
    const int wave  = tid >> 6;           // 0..3
    const int base  = b * NP;
    const int tbase = base + thalf * NT;  // global index of first staged target

    if (tid < 8) spack[NT * 8 + tid] = 0;   // zero line for high-half lanes

    // ---- pack 2048 targets: [t_hi xyz, t_lo xyz, t2_hi, t2_lo] bf16x8 ----
    #pragma unroll 4
    for (int k = 0; k < 8; ++k) {
        int j = tid + k * 256;
        float x, y, z;
        if (dir == 0) {                       // targets = normalized gt
            const float* row = label + (size_t)(tbase + j) * 5;
            x = fmaf(row[1], INV128, -1.0f);
            y = fmaf(row[2], INV128, -1.0f);
            z = fmaf(row[3], INV128, -1.0f);
        } else {                              // targets = raw gen
            const float* g = gen + (size_t)(tbase + j) * 3;
            x = g[0]; y = g[1]; z = g[2];
        }
        float t2 = fmaf(x, x, fmaf(y, y, z * z));
        short xh = bf16rne(x), yh = bf16rne(y), zh = bf16rne(z);
        short xl = bf16rne(x - bf2f(xh));
        short yl = bf16rne(y - bf2f(yh));
        short zl2 = bf16rne(z - bf2f(zh));
        short th = bf16rne(t2);
        short tl = bf16rne(t2 - bf2f(th));
        bf16x8 v = {xh, yh, zh, xl, yl, zl2, th, tl};
        *(bf16x8*)(spack + j * 8) = v;
    }
    __syncthreads();                          // spack is read-only from here on

    const f32x16 zc = {};

    #pragma unroll 1
    for (int sub = 0; sub < 2; ++sub) {
        // ---- per-lane query fragment: rows = lane&31, k8-15 zero ----
        const int qrow = base + qpair * 256 + sub * 128 + wave * 32 + (lane & 31);
        float q2 = 0.0f;
        bf16x8 afrag = (bf16x8)(short)0;
        if (lane < 32) {
            float x, y, z;
            if (dir == 0) {                   // queries = raw gen
                const float* g = gen + (size_t)qrow * 3;
                x = g[0]; y = g[1]; z = g[2];
            } else {                          // queries = normalized gt
                const float* row = label + (size_t)qrow * 5;
                x = fmaf(row[1], INV128, -1.0f);
                y = fmaf(row[2], INV128, -1.0f);
                z = fmaf(row[3], INV128, -1.0f);
            }
            q2 = fmaf(x, x, fmaf(y, y, z * z));  // exact fp32, added after min
            short ax = bf16rne(-2.0f * x), ay = bf16rne(-2.0f * y), az = bf16rne(-2.0f * z);
            const short one = 0x3F80;         // bf16 1.0
            bf16x8 a = {ax, ay, az, ax, ay, az, one, one};
            afrag = a;
        }

        float mn[16];
        #pragma unroll
        for (int r = 0; r < 16; ++r) mn[r] = FINF;

        // ---- stream 64 col-tiles, 4/iter, register double-buffered ----
        const short* zl = spack + NT * 8;
        const short* p0 = (lane < 32) ? (spack + (lane & 31) * 8)       : zl;
        const short* p1 = (lane < 32) ? (spack + (lane & 31) * 8 + 256) : zl;
        const short* p2 = (lane < 32) ? (spack + (lane & 31) * 8 + 512) : zl;
        const short* p3 = (lane < 32) ? (spack + (lane & 31) * 8 + 768) : zl;
        const int step = (lane < 32) ? 1024 : 0;   // 4 tiles = 128 cols * 8 shorts

        bf16x8 b0 = *(const bf16x8*)p0;
        bf16x8 b1 = *(const bf16x8*)p1;
        bf16x8 b2 = *(const bf16x8*)p2;
        bf16x8 b3 = *(const bf16x8*)p3;
        #pragma unroll 2
        for (int it = 0; it < 16; ++it) {
            p0 += step; p1 += step; p2 += step; p3 += step;
            bf16x8 n0 = *(const bf16x8*)p0;   // last iter: dead reads into pad
            bf16x8 n1 = *(const bf16x8*)p1;
            bf16x8 n2 = *(const bf16x8*)p2;
            bf16x8 n3 = *(const bf16x8*)p3;
            f32x16 c0 = __builtin_amdgcn_mfma_f32_32x32x16_bf16(afrag, b0, zc, 0, 0, 0);
            f32x16 c1 = __builtin_amdgcn_mfma_f32_32x32x16_bf16(afrag, b1, zc, 0, 0, 0);
            f32x16 c2 = __builtin_amdgcn_mfma_f32_32x32x16_bf16(afrag, b2, zc, 0, 0, 0);
            f32x16 c3 = __builtin_amdgcn_mfma_f32_32x32x16_bf16(afrag, b3, zc, 0, 0, 0);
            #pragma unroll
            for (int r = 0; r < 16; ++r) {
                mn[r] = fminf(fminf(c0[r], c1[r]),
                              fminf(fminf(c2[r], c3[r]), mn[r]));
            }
            b0 = n0; b1 = n1; b2 = n2; b3 = n3;
        }

        // ---- fold 32 column-classes (butterfly within each 32-lane half) ----
        #pragma unroll
        for (int m = 1; m <= 16; m <<= 1) {
            #pragma unroll
            for (int r = 0; r < 16; ++r)
                mn[r] = fminf(mn[r], __shfl_xor(mn[r], m, 64));
        }

        // ---- write per-row (mn + q2): lanes c=0..15 of each half write mn[c]
        // C/D layout: row(r) = (r&3) + 8*(r>>2) + 4*(lane>>5).
        const int h4 = (lane >> 5) * 4;
        const int c  = lane & 31;
        const int row = (c & 3) + 8 * (c >> 2) + h4;     // valid for c<16
        float q2r = __shfl(q2, row & 31, 64);            // all lanes participate
        float v = mn[0];
        #pragma unroll
        for (int r = 1; r < 16; ++r) if (c == r) v = mn[r];  // cndmask chain
        if (c < 16) {
            size_t gidx = (size_t)thalf * NROWS
                        + (size_t)(((dir * NB + b) << 12) + qpair * 256 + sub * 128
                                   + wave * 32 + row);
            rowmins[gidx] = v + q2r;
        }
    }
}

// 512 blocks x 256 threads: pairwise min over target halves, then block sum.
__global__ __launch_bounds__(256) void minsum_kernel(const float* __restrict__ rowmins,
                                                     float* __restrict__ partial2) {
    const int tid = threadIdx.x;
    const int row = blockIdx.x * 256 + tid;
    float s = fminf(rowmins[row], rowmins[NROWS + row]);
    #pragma unroll
    for (int off = 32; off > 0; off >>= 1) s += __shfl_down(s, off, 64);
    __shared__ float w4[4];
    if ((tid & 63) == 0) w4[tid >> 6] = s;
    __syncthreads();
    if (tid == 0) partial2[blockIdx.x] = ((w4[0] + w4[1]) + (w4[2] + w4[3]));
}

__global__ __launch_bounds__(256) void reduce_kernel(const float* __restrict__ partial,
                                                     float* __restrict__ out) {
    int i = threadIdx.x;
    float s = partial[i] + partial[i + 256];  // 512 block partials
    #pragma unroll
    for (int off = 32; off > 0; off >>= 1) s += __shfl_down(s, off, 64);
    __shared__ float ws4[4];
    if ((i & 63) == 0) ws4[i >> 6] = s;
    __syncthreads();
    if (i == 0) out[0] = ((ws4[0] + ws4[1]) + (ws4[2] + ws4[3])) * (1.0f / 65536.0f);
}

extern "C" void kernel_launch(void* const* d_in, const int* in_sizes, int n_in,
                              void* d_out, int out_size, void* d_ws, size_t ws_size,
                              hipStream_t stream) {
    const float* gen   = (const float*)d_in[0];   // [B*P, 3] fp32
    // d_in[1] = batch_gen (int32) — unused: segments are contiguous equal-size
    const float* label = (const float*)d_in[2];   // [B*Q, 5] fp32
    float* rowmins  = (float*)d_ws;               // 2*131072 floats = 1 MB
    float* partial2 = rowmins + 2 * NROWS;        // 512 floats
    float* out = (float*)d_out;

    chamfer_kernel<<<1024, THREADS, 0, stream>>>(gen, label, rowmins);
    minsum_kernel<<<512, 256, 0, stream>>>(rowmins, partial2);
    reduce_kernel<<<1, 256, 0, stream>>>(partial2, out);
}

// Round 6
// 87.537 us; speedup vs baseline: 1.0724x; 1.0724x over previous
//
#include <hip/hip_runtime.h>

// Chamfer reconstruction loss, B=16, P=Q=4096, 3-D points, via bf16 MFMA.
//
// R15: transposed reuse — ONE distance matrix per batch serves BOTH
// directions. dir0 = row-mins of D[gen x gt], dir1 = col-mins of the
// SAME matrix; R9..R14 computed D twice. This halves MFMA, LDS
// streaming, and per-element VALU overhead (the counters show ~3x more
// VALU cycles than the visible ops, scaling with elements produced, and
// pinned 41us across three occupancy-different variants).
//
// To allow col-mins, |q|^2 moves IN-matrix via the unused k8-15 slots:
// high lanes' A = {q2_hi, q2_lo, 0...}, high lanes' B = constant
// {1,1,0...} line in LDS (the former zero line). Element = full
// d(i,j) = -2q.(t_hi+t_lo) + (t2_hi+t2_lo) + (q2_hi+q2_lo), all to
// ~2^-17 except the A-side single-bf16 q perturbation (value-safe:
// ~5e-4 zero-mean, threshold 1e-2).
//
// Per 32x32 tile: row-min into mn[16] (as before) + col-fold (16->1
// fmin tree, both halves) -> LDS atomicMin on float_as_int(d+1.0f)
// (d+1>0 so int order == float order). Block = 256 gen rows x 2048 gt
// cols; grid 512 = 16b x 16 rowslabs x 2 colslabs. Row-mins combined
// across 2 colslabs, col-mins across 16 rowslabs, by combine_kernel.

#define NB 16
#define NP 4096
#define NT 2048          // gt cols staged per block
#define THREADS 256
#define NROWST 65536     // 16 b * 4096 gen rows
#define INV128 0.0078125f   // gt normalize: c/128 - 1
#define FINF __int_as_float(0x7F800000)

typedef __attribute__((ext_vector_type(8)))  short bf16x8;
typedef __attribute__((ext_vector_type(16))) float f32x16;

__device__ __forceinline__ short bf16rne(float f) {
    unsigned u = __float_as_uint(f);
    return (short)((u + 0x7FFFu + ((u >> 16) & 1u)) >> 16);
}
__device__ __forceinline__ float bf2f(short s) {
    return __uint_as_float(((unsigned)(unsigned short)s) << 16);
}
__device__ __forceinline__ float fold16(const f32x16& c) {
    float a = fminf(fminf(c[0], c[1]),  fminf(c[2],  c[3]));
    float b = fminf(fminf(c[4], c[5]),  fminf(c[6],  c[7]));
    float d = fminf(fminf(c[8], c[9]),  fminf(c[10], c[11]));
    float e = fminf(fminf(c[12], c[13]), fminf(c[14], c[15]));
    return fminf(fminf(a, b), fminf(d, e));
}

// grid = 512: b = bid>>5, rs = (bid>>1)&15, cs = bid&1.
// Block: gen rows [rs*256, +256) x gt cols [cs*2048, +2048) of batch b.
__global__ __launch_bounds__(THREADS) void chamfer_kernel(const float* __restrict__ gen,
                                                          const float* __restrict__ label,
                                                          float* __restrict__ rowws,
                                                          int* __restrict__ colws) {
    // 32KB pack + ones line + prefetch-overrun pad + 8KB col-min keys
    __shared__ short spack[NT * 8 + 1280];
    __shared__ int colmin[NT];

    const int bid  = blockIdx.x;
    const int b    = bid >> 5;
    const int rs   = (bid >> 1) & 15;
    const int cs   = bid & 1;
    const int tid  = threadIdx.x;
    const int lane = tid & 63;
    const int wave = tid >> 6;            // 0..3
    const int base  = b * NP;
    const int tbase = base + cs * NT;     // first staged gt point

    // ones line for high-half lanes: B k8-15 = {1,1,0,...} pairs with
    // A high-lane {q2h,q2l,0,...} to add |q|^2 into every element.
    if (tid < 8) spack[NT * 8 + tid] = (tid < 2) ? (short)0x3F80 : (short)0;

    #pragma unroll
    for (int k = 0; k < 8; ++k) colmin[tid + k * 256] = 0x7F800000;  // +inf key

    // ---- pack 2048 gt targets: [t_hi xyz, t_lo xyz, t2_hi, t2_lo] ----
    #pragma unroll 4
    for (int k = 0; k < 8; ++k) {
        int j = tid + k * 256;
        const float* row = label + (size_t)(tbase + j) * 5;
        float x = fmaf(row[1], INV128, -1.0f);
        float y = fmaf(row[2], INV128, -1.0f);
        float z = fmaf(row[3], INV128, -1.0f);
        float t2 = fmaf(x, x, fmaf(y, y, z * z));
        short xh = bf16rne(x), yh = bf16rne(y), zh = bf16rne(z);
        short xl = bf16rne(x - bf2f(xh));
        short yl = bf16rne(y - bf2f(yh));
        short zl = bf16rne(z - bf2f(zh));
        short th = bf16rne(t2);
        short tl = bf16rne(t2 - bf2f(th));
        bf16x8 v = {xh, yh, zh, xl, yl, zl, th, tl};
        *(bf16x8*)(spack + j * 8) = v;
    }
    __syncthreads();                      // spack + colmin ready

    const f32x16 zc = {};

    #pragma unroll 1
    for (int sub = 0; sub < 2; ++sub) {
        // ---- per-lane query (gen) fragment: rows = lane&31 ----
        const int qrow = base + rs * 256 + sub * 128 + wave * 32 + (lane & 31);
        const float* g = gen + (size_t)qrow * 3;
        float x = g[0], y = g[1], z = g[2];
        float q2 = fmaf(x, x, fmaf(y, y, z * z));
        bf16x8 afrag;
        if (lane < 32) {                  // k0-7: -2q twice + 1,1 for t2
            short ax = bf16rne(-2.0f * x), ay = bf16rne(-2.0f * y), az = bf16rne(-2.0f * z);
            const short one = 0x3F80;
            bf16x8 a = {ax, ay, az, ax, ay, az, one, one};
            afrag = a;
        } else {                          // k8-15: q2 hi/lo against B ones
            short qh = bf16rne(q2);
            short ql = bf16rne(q2 - bf2f(qh));
            bf16x8 a = {qh, ql, 0, 0, 0, 0, 0, 0};
            afrag = a;
        }

        float mn[16];
        #pragma unroll
        for (int r = 0; r < 16; ++r) mn[r] = FINF;

        // ---- stream 64 col-tiles, 4/iter, register double-buffered ----
        const short* ol = spack + NT * 8;     // ones line (high lanes)
        const short* p0 = (lane < 32) ? (spack + (lane & 31) * 8)       : ol;
        const short* p1 = (lane < 32) ? (spack + (lane & 31) * 8 + 256) : ol;
        const short* p2 = (lane < 32) ? (spack + (lane & 31) * 8 + 512) : ol;
        const short* p3 = (lane < 32) ? (spack + (lane & 31) * 8 + 768) : ol;
        const int step = (lane < 32) ? 1024 : 0;   // 4 tiles = 128 cols * 8 shorts

        bf16x8 b0 = *(const bf16x8*)p0;
        bf16x8 b1 = *(const bf16x8*)p1;
        bf16x8 b2 = *(const bf16x8*)p2;
        bf16x8 b3 = *(const bf16x8*)p3;
        #pragma unroll 2
        for (int it = 0; it < 16; ++it) {
            p0 += step; p1 += step; p2 += step; p3 += step;
            bf16x8 n0 = *(const bf16x8*)p0;   // last iter: dead reads into pad
            bf16x8 n1 = *(const bf16x8*)p1;
            bf16x8 n2 = *(const bf16x8*)p2;
            bf16x8 n3 = *(const bf16x8*)p3;
            f32x16 c0 = __builtin_amdgcn_mfma_f32_32x32x16_bf16(afrag, b0, zc, 0, 0, 0);
            f32x16 c1 = __builtin_amdgcn_mfma_f32_32x32x16_bf16(afrag, b1, zc, 0, 0, 0);
            f32x16 c2 = __builtin_amdgcn_mfma_f32_32x32x16_bf16(afrag, b2, zc, 0, 0, 0);
            f32x16 c3 = __builtin_amdgcn_mfma_f32_32x32x16_bf16(afrag, b3, zc, 0, 0, 0);
            // row-mins (min over cols, per output row-class)
            #pragma unroll
            for (int r = 0; r < 16; ++r) {
                mn[r] = fminf(fminf(c0[r], c1[r]),
                              fminf(fminf(c2[r], c3[r]), mn[r]));
            }
            // col-mins (min over this wave's 32 rows, per col): fold 16
            // regs -> 1, then LDS atomicMin of float_as_int(d+1) — both
            // lane halves hit the same col (2-way, HW-serialized).
            const int cb = it * 128 + (lane & 31);
            atomicMin(&colmin[cb],       __float_as_int(fold16(c0) + 1.0f));
            atomicMin(&colmin[cb + 32],  __float_as_int(fold16(c1) + 1.0f));
            atomicMin(&colmin[cb + 64],  __float_as_int(fold16(c2) + 1.0f));
            atomicMin(&colmin[cb + 96],  __float_as_int(fold16(c3) + 1.0f));
            b0 = n0; b1 = n1; b2 = n2; b3 = n3;
        }

        // ---- fold 32 column-classes (butterfly within each 32-lane half) ----
        #pragma unroll
        for (int m = 1; m <= 16; m <<= 1) {
            #pragma unroll
            for (int r = 0; r < 16; ++r)
                mn[r] = fminf(mn[r], __shfl_xor(mn[r], m, 64));
        }

        // ---- write per-row min (mn already includes q2) ----
        // C/D layout: row = (r&3) + 8*(r>>2) + 4*(lane>>5), col = lane&31.
        const int h4 = (lane >> 5) * 4;
        const int c  = lane & 31;
        const int row = (c & 3) + 8 * (c >> 2) + h4;     // valid for c<16
        float v = mn[0];
        #pragma unroll
        for (int r = 1; r < 16; ++r) if (c == r) v = mn[r];  // cndmask chain
        if (c < 16)
            rowws[cs * NROWST + base + rs * 256 + sub * 128 + wave * 32 + row] = v;
    }

    __syncthreads();                      // all col atomics done
    const int cwbase = ((b * 2 + cs) * 16 + rs) * NT;
    #pragma unroll
    for (int k = 0; k < 8; ++k)
        colws[cwbase + tid + k * 256] = colmin[tid + k * 256];
}

// grid 512: bid<256 -> row-mins (min over 2 colslabs, already include q2);
//           bid>=256 -> col-mins (min over 16 rowslab int keys, decode).
__global__ __launch_bounds__(256) void combine_kernel(const float* __restrict__ rowws,
                                                      const int* __restrict__ colws,
                                                      float* __restrict__ partial2) {
    const int tid = threadIdx.x;
    const int bid = blockIdx.x;
    float s;
    if (bid < 256) {
        int row = bid * 256 + tid;        // 0..65535
        s = fminf(rowws[row], rowws[NROWST + row]);
    } else {
        int gidx = (bid - 256) * 256 + tid;   // global gt col 0..65535
        const int* cw = colws + (gidx >> 11) * (16 * NT) + (gidx & (NT - 1));
        int k = cw[0];
        #pragma unroll
        for (int r2 = 1; r2 < 16; ++r2) k = min(k, cw[r2 * NT]);
        s = __int_as_float(k) - 1.0f;     // undo the +1 positivity shift
    }
    #pragma unroll
    for (int off = 32; off > 0; off >>= 1) s += __shfl_down(s, off, 64);
    __shared__ float w4[4];
    if ((tid & 63) == 0) w4[tid >> 6] = s;
    __syncthreads();
    if (tid == 0) partial2[bid] = (w4[0] + w4[1]) + (w4[2] + w4[3]);
}

__global__ __launch_bounds__(256) void reduce_kernel(const float* __restrict__ partial,
                                                     float* __restrict__ out) {
    int i = threadIdx.x;
    float s = partial[i] + partial[i + 256];  // 512 partials
    #pragma unroll
    for (int off = 32; off > 0; off >>= 1) s += __shfl_down(s, off, 64);
    __shared__ float ws4[4];
    if ((i & 63) == 0) ws4[i >> 6] = s;
    __syncthreads();
    if (i == 0) out[0] = ((ws4[0] + ws4[1]) + (ws4[2] + ws4[3])) * (1.0f / 65536.0f);
}

extern "C" void kernel_launch(void* const* d_in, const int* in_sizes, int n_in,
                              void* d_out, int out_size, void* d_ws, size_t ws_size,
                              hipStream_t stream) {
    const float* gen   = (const float*)d_in[0];   // [B*P, 3] fp32
    // d_in[1] = batch_gen (int32) — unused: segments are contiguous equal-size
    const float* label = (const float*)d_in[2];   // [B*Q, 5] fp32
    float* rowws    = (float*)d_ws;               // 2*65536 floats  (512 KB)
    int*   colws    = (int*)d_ws + 2 * NROWST;    // 16b*2cs*16rs*2048 ints (4 MB)
    float* partial2 = (float*)d_ws + 2 * NROWST + NB * 2 * 16 * NT;  // 512 floats
    float* out = (float*)d_out;

    chamfer_kernel<<<512, THREADS, 0, stream>>>(gen, label, rowws, colws);
    combine_kernel<<<512, 256, 0, stream>>>(rowws, colws, partial2);
    reduce_kernel<<<1, 256, 0, stream>>>(partial2, out);
}